// Round 8
// baseline (210.033 us; speedup 1.0000x reference)
//
#include <hip/hip_runtime.h>
#include <stdint.h>

// Blocksparse Deep ReLU GAM forward via chained f16 MFMA.
// 128 towers, each 2->16->12->8->1 MLP over input pair (2t, 2t+1);
// out[s] = sum_t tower_t(x[s]) + bias. shape_loss output = zeros(128).
//
// v_mfma_f32_16x16x16_f16 D layout (row=(lane>>4)*4+reg, col=lane&15)
// equals the B layout (k=(lane>>4)*4+i, col=lane&15), so Y = W·X chains
// layer-to-layer with only lane-local relu + f32->f16 cvt.
//
// Round 8: layer-batched schedule. Per u, Stage A = all 16 towers'
// L0+L1 (16 independent 2-MFMA chains, h1 stashed in 32 VGPRs), Stage B
// = all 16 towers' L2+L3. 16-way ILP hides the MFMA->relu->MFMA chain
// latency that the tower-major loop exposed. b2 rides the layer-2 C
// operand (no cndmask); L3 acc split even/odd to break the serial
// acc-MFMA chain; out-zeroing folded into pack_frags (one less launch).
//
// 4-tower shared B0: lane (kg,col) carries B0 rows 4kg..4kg+2 =
// {x[s][2(tb+kg)], x[s][2(tb+kg)+1], 1}; tower tb+j's A0 is nonzero only
// in k-columns 4j..4j+2, so one coalesced all-lane x load feeds 4 towers.
//
// Bias: b0 -> A0 k=4j+2 (homogeneous coord); b1 -> C of L1 MFMA;
// b2 -> C of L2 MFMA; sum_t b3[t] + bias -> one scalar at the end.

constexpr int BATCH = 32768;
constexpr int FEAT  = 256;
constexpr int NTOW  = 128;
constexpr int U     = 4;    // 16-sample tiles per wave
constexpr int OUTN  = BATCH + NTOW;   // out + shape_loss

constexpr int REC = 544;  // dwords per tower record (2176 B, 16B-aligned)
// record layout (dword offsets): [0,512) = 64 lanes x 8 dwords
// {a0.lo,a0.hi,a1.lo,a1.hi,a2.lo,a2.hi,a3.lo,a3.hi};
// [512,528) = b1 f32[16]; [528,544) = b2 f32[16] (rows 8..15 = 0).
constexpr int OFF_B1 = 512, OFF_B2 = 528;

typedef _Float16 h4_t __attribute__((ext_vector_type(4)));
typedef __fp16   hp2_t __attribute__((ext_vector_type(2)));
typedef float    f4_t __attribute__((ext_vector_type(4)));

static __device__ __forceinline__ h4_t u2_to_h4(uint32_t lo, uint32_t hi) {
  union { uint2 u; h4_t h; } cv; cv.u.x = lo; cv.u.y = hi; return cv.h;
}
static __device__ __forceinline__ void h4_to_u2(h4_t v, uint32_t* d) {
  union { h4_t h; uint2 u; } cv; cv.h = v; d[0] = cv.u.x; d[1] = cv.u.y;
}
// pack 4 f32 -> 4 f16 (2x v_cvt_pkrtz) then packed relu (v_pk_max_f16 x2).
// relu(cvt(x)) == cvt(relu(x)): RTZ preserves sign; -0 is harmless in dots.
static __device__ __forceinline__ h4_t relu_pack4(const f4_t d) {
  const hp2_t lo = __builtin_amdgcn_cvt_pkrtz(d[0], d[1]);
  const hp2_t hi = __builtin_amdgcn_cvt_pkrtz(d[2], d[3]);
  h4_t r;
  r[0] = (_Float16)lo[0]; r[1] = (_Float16)lo[1];
  r[2] = (_Float16)hi[0]; r[3] = (_Float16)hi[1];
  const h4_t z = {(_Float16)0.f, (_Float16)0.f, (_Float16)0.f, (_Float16)0.f};
  return __builtin_elementwise_max(r, z);
}

__global__ void pack_frags(
    const float* __restrict__ W0, const float* __restrict__ B0,
    const float* __restrict__ W1, const float* __restrict__ B1,
    const float* __restrict__ W2, const float* __restrict__ B2,
    const float* __restrict__ W3, const float* __restrict__ B3,
    const float* __restrict__ bias, uint32_t* __restrict__ pack,
    float* __restrict__ out) {
  const int t   = blockIdx.x;
  const int l   = threadIdx.x;      // 64 threads = 64 lanes
  const int row = l & 15;           // A-frag row  = lane&15
  const int kg  = l >> 4;           // A-frag k    = (lane>>4)*4 + r
  uint32_t* rec = pack + t * REC;

  // Zero the output buffer (out[0:BATCH] accumulated by atomics;
  // shape_loss[BATCH:BATCH+NTOW] stays 0). Grid-stride over all blocks.
  for (int i = t * 64 + l; i < OUTN; i += NTOW * 64) out[i] = 0.f;

  h4_t a0, a1, a2, a3;
#pragma unroll
  for (int r = 0; r < 4; ++r) {
    const int k = kg * 4 + r;
    // A0: tower t occupies k-columns 4*(t&3) .. 4*(t&3)+2.
    float v0 = 0.f;
    if (kg == (t & 3)) {
      if (r < 2)       v0 = W0[(16*t + row) * FEAT + 2*t + r];
      else if (r == 2) v0 = B0[16*t + row];
    }
    a0[r] = (_Float16)v0;

    float v1 = 0.f;
    if (row < 12)    v1 = W1[(12*t + row) * (16*NTOW) + 16*t + k];
    a1[r] = (_Float16)v1;

    float v2 = 0.f;
    if (row < 8 && k < 12) v2 = W2[(8*t + row) * (12*NTOW) + 12*t + k];
    a2[r] = (_Float16)v2;

    float v3 = 0.f;
    if (row == 0 && k < 8) v3 = W3[t * (8*NTOW) + 8*t + k];
    a3[r] = (_Float16)v3;
  }
  uint32_t* lrec = rec + 8 * l;
  h4_to_u2(a0, lrec + 0);
  h4_to_u2(a1, lrec + 2);
  h4_to_u2(a2, lrec + 4);
  h4_to_u2(a3, lrec + 6);

  if (l < 16) {
    const float b1v = (l < 12) ? B1[12*t + l] : 0.f;
    rec[OFF_B1 + l] = __float_as_uint(b1v);
    const float b2v = (l < 8) ? B2[8*t + l] : 0.f;
    rec[OFF_B2 + l] = __float_as_uint(b2v);
  }
  if (t == 0 && l == 0) {
    float s = bias[0];
    for (int j = 0; j < NTOW; ++j) s += B3[j];
    pack[NTOW * REC] = __float_as_uint(s);
  }
}

// One wave: tower group g (16 towers), U tiles of 16 samples.
__global__ __launch_bounds__(256, 4) void bs_mfma(
    const float* __restrict__ x, const uint32_t* __restrict__ pack,
    float* __restrict__ out) {
  const int wid   = blockIdx.x * 4 + (threadIdx.x >> 6);
  const int lane  = threadIdx.x & 63;
  const int col   = lane & 15;       // sample within tile
  const int kg    = lane >> 4;
  const int g     = wid & 7;         // tower group: towers [16g, 16g+16)
  const int sbase = (wid >> 3) * (16 * U);

  const float cbias = __uint_as_float(pack[NTOW * REC]);
  const f4_t zc = {0.f, 0.f, 0.f, 0.f};

  // Per-lane x base: sample row (sbase+col), feature 2*(16g + kg).
  const float* __restrict__ xb =
      x + (size_t)(sbase + col) * FEAT + 2 * (g * 16 + kg);

  const uint32_t* __restrict__ fp  = pack + (size_t)(g * 16) * REC + 8 * lane;
  const uint32_t* __restrict__ bp1 = pack + (size_t)(g * 16) * REC + OFF_B1 + kg * 4;
  const uint32_t* __restrict__ bp2 = pack + (size_t)(g * 16) * REC + OFF_B2 + kg * 4;

  f4_t accA[U], accB[U];
#pragma unroll
  for (int u = 0; u < U; ++u) { accA[u] = zc; accB[u] = zc; }

#pragma unroll
  for (int u = 0; u < U; ++u) {
    // ---- b0 fragments for this u (4 packs of 4 towers) ----
    h4_t b0[4];
#pragma unroll
    for (int p = 0; p < 4; ++p) {
      const float2 xv = *(const float2*)(xb + 8 * p + (size_t)u * 16 * FEAT);
      const hp2_t xh = __builtin_amdgcn_cvt_pkrtz(xv.x, xv.y);
      h4_t b;
      b[0] = (_Float16)xh[0];
      b[1] = (_Float16)xh[1];
      b[2] = (_Float16)1.0f;
      b[3] = (_Float16)0.0f;
      b0[p] = b;
    }

    // ---- Stage A: all 16 towers' L0+L1; stash h1 ----
    h4_t h1v[16];
#pragma unroll
    for (int j = 0; j < 16; ++j) {
      const uint4  w01 = *(const uint4*)(fp + j * REC);      // a0|a1
      const float4 bb1 = *(const float4*)(bp1 + j * REC);
      const h4_t a0 = u2_to_h4(w01.x, w01.y);
      const h4_t a1 = u2_to_h4(w01.z, w01.w);
      const f4_t c1 = {bb1.x, bb1.y, bb1.z, bb1.w};

      const f4_t d0 = __builtin_amdgcn_mfma_f32_16x16x16f16(a0, b0[j >> 2], zc, 0, 0, 0);
      const h4_t h0 = relu_pack4(d0);
      const f4_t d1 = __builtin_amdgcn_mfma_f32_16x16x16f16(a1, h0, c1, 0, 0, 0);
      h1v[j] = relu_pack4(d1);
    }

    // ---- Stage B: all 16 towers' L2+L3; split acc chains ----
#pragma unroll
    for (int j = 0; j < 16; ++j) {
      const uint4  w23 = *(const uint4*)(fp + j * REC + 4);  // a2|a3
      const float4 bb2 = *(const float4*)(bp2 + j * REC);
      const h4_t a2 = u2_to_h4(w23.x, w23.y);
      const h4_t a3 = u2_to_h4(w23.z, w23.w);
      const f4_t c2 = {bb2.x, bb2.y, bb2.z, bb2.w};

      const f4_t d2 = __builtin_amdgcn_mfma_f32_16x16x16f16(a2, h1v[j], c2, 0, 0, 0);
      const h4_t h2 = relu_pack4(d2);
      if (j & 1)
        accB[u] = __builtin_amdgcn_mfma_f32_16x16x16f16(a3, h2, accB[u], 0, 0, 0);
      else
        accA[u] = __builtin_amdgcn_mfma_f32_16x16x16f16(a3, h2, accA[u], 0, 0, 0);
    }
  }

  if (kg == 0) {
    const float add = (g == 0) ? cbias : 0.f;
#pragma unroll
    for (int u = 0; u < U; ++u)
      atomicAdd(out + sbase + u * 16 + col, accA[u][0] + accB[u][0] + add);
  }
}

// ---- correctness-only fallback (ws too small; never expected) ----
__device__ __forceinline__ float gather_weight(
    int t, int i,
    const float* __restrict__ W0, const float* __restrict__ B0,
    const float* __restrict__ W1, const float* __restrict__ B1,
    const float* __restrict__ W2, const float* __restrict__ B2,
    const float* __restrict__ W3, const float* __restrict__ B3) {
  float v = 0.f;
  if (i < 32)       { int r = i >> 1, c = i & 1;               v = W0[(16*t + r)*FEAT + 2*t + c]; }
  else if (i < 48)  {                                           v = B0[16*t + (i - 32)]; }
  else if (i < 240) { int k = i - 48, r = k >> 4, c = k & 15;   v = W1[(12*t + r)*(16*NTOW) + 16*t + c]; }
  else if (i < 252) {                                           v = B1[12*t + (i - 240)]; }
  else if (i < 348) { int k = i - 252, r = k / 12, c = k - 12*r; v = W2[(8*t + r)*(12*NTOW) + 12*t + c]; }
  else if (i < 356) {                                           v = B2[8*t + (i - 348)]; }
  else if (i < 364) {                                           v = W3[t*(8*NTOW) + 8*t + (i - 356)]; }
  else if (i == 364){                                           v = B3[t]; }
  return v;
}

__global__ void bs_fwd_slow(
    const float* __restrict__ x,
    const float* __restrict__ W0, const float* __restrict__ B0,
    const float* __restrict__ W1, const float* __restrict__ B1,
    const float* __restrict__ W2, const float* __restrict__ B2,
    const float* __restrict__ W3, const float* __restrict__ B3,
    const float* __restrict__ bias,
    float* __restrict__ out) {
  const int s = blockIdx.x * blockDim.x + threadIdx.x;
  if (s >= BATCH) return;
  float acc = bias[0];
  for (int t = 0; t < NTOW; ++t) {
    float h0[16], h1[12], h2[8];
    const float x0 = x[(size_t)s*FEAT + 2*t], x1 = x[(size_t)s*FEAT + 2*t + 1];
    for (int r = 0; r < 16; ++r)
      h0[r] = fmaxf(0.f, gather_weight(t, 2*r, W0,B0,W1,B1,W2,B2,W3,B3) * x0
                        + gather_weight(t, 2*r+1, W0,B0,W1,B1,W2,B2,W3,B3) * x1
                        + gather_weight(t, 32+r, W0,B0,W1,B1,W2,B2,W3,B3));
    for (int r = 0; r < 12; ++r) {
      float sum = gather_weight(t, 240+r, W0,B0,W1,B1,W2,B2,W3,B3);
      for (int c = 0; c < 16; ++c)
        sum += gather_weight(t, 48+16*r+c, W0,B0,W1,B1,W2,B2,W3,B3) * h0[c];
      h1[r] = fmaxf(0.f, sum);
    }
    for (int r = 0; r < 8; ++r) {
      float sum = gather_weight(t, 348+r, W0,B0,W1,B1,W2,B2,W3,B3);
      for (int c = 0; c < 12; ++c)
        sum += gather_weight(t, 252+12*r+c, W0,B0,W1,B1,W2,B2,W3,B3) * h1[c];
      h2[r] = fmaxf(0.f, sum);
    }
    float sum = gather_weight(t, 364, W0,B0,W1,B1,W2,B2,W3,B3);
    for (int c = 0; c < 8; ++c)
      sum += gather_weight(t, 356+c, W0,B0,W1,B1,W2,B2,W3,B3) * h2[c];
    acc += sum;
  }
  out[s] = acc;
}

extern "C" void kernel_launch(void* const* d_in, const int* in_sizes, int n_in,
                              void* d_out, int out_size, void* d_ws, size_t ws_size,
                              hipStream_t stream) {
  const float* x    = (const float*)d_in[0];
  const float* W0   = (const float*)d_in[1];
  const float* B0   = (const float*)d_in[2];
  const float* W1   = (const float*)d_in[3];
  const float* B1   = (const float*)d_in[4];
  const float* W2   = (const float*)d_in[5];
  const float* B2   = (const float*)d_in[6];
  const float* W3   = (const float*)d_in[7];
  const float* B3   = (const float*)d_in[8];
  const float* bias = (const float*)d_in[9];
  float* out = (float*)d_out;

  const size_t packBytes = ((size_t)NTOW * REC + 1) * sizeof(uint32_t);

  if (ws_size >= packBytes) {
    uint32_t* pack = (uint32_t*)d_ws;
    // pack_frags also zeroes out[] (atomics accumulate; shape_loss stays 0).
    pack_frags<<<NTOW, 64, 0, stream>>>(W0, B0, W1, B1, W2, B2, W3, B3, bias, pack, out);
    const int waves = (BATCH / (16 * U)) * 8;     // 4096 waves
    bs_mfma<<<waves / 4, 256, 0, stream>>>(x, pack, out);
  } else {
    (void)hipMemsetAsync(d_out, 0, (size_t)out_size * sizeof(float), stream);
    bs_fwd_slow<<<BATCH / 256, 256, 0, stream>>>(x, W0, B0, W1, B1, W2, B2, W3, B3, bias, out);
  }
}

// Round 9
// 49.178 us; speedup vs baseline: 4.2709x; 4.2709x over previous
//
#include <hip/hip_runtime.h>
#include <stdint.h>

// Blocksparse Deep ReLU GAM forward via chained f16 MFMA.
// 128 towers, each 2->16->12->8->1 MLP over input pair (2t, 2t+1);
// out[s] = sum_t tower_t(x[s]) + bias. shape_loss output = zeros(128).
//
// v_mfma_f32_16x16x16_f16 D layout (row=(lane>>4)*4+reg, col=lane&15)
// equals the B layout (k=(lane>>4)*4+i, col=lane&15), so Y = W·X chains
// layer-to-layer with only lane-local relu + f32->f16 cvt.
//
// Round 9: r7 skeleton + pair-wise stage split, spill-proof.
//  - Towers processed 2 at a time: Stage A = both towers' L0+L1 for all
//    U tiles (8 independent 2-MFMA chains; h1 stash in 16 VGPR), Stage B
//    = both towers' L2+L3. 2x the in-flight chains of r7's tower-major
//    loop; all arrays are small, statically indexed, #pragma unroll'd
//    (r8's 16-tower stash spilled to scratch: 295 MB WRITE_SIZE).
//  - L3 accumulation: C=0 MFMA + scalar add of d[0] into float accv[U].
//    Breaks the serial acc-MFMA chain and saves 24 VGPR (only row 0 of
//    the L3 product is nonzero; kg!=0 lanes add structural zeros).
//  - b2 rides the L2 C operand (no cndmask); out-zeroing folded into
//    pack_frags (no separate memset dispatch).
//
// 4-tower shared B0: lane (kg,col) carries B0 rows 4kg..4kg+2 =
// {x[s][2(tb+kg)], x[s][2(tb+kg)+1], 1}; tower tb+j's A0 is nonzero only
// in k-columns 4j..4j+2, so one coalesced all-lane x load feeds 4 towers.
//
// Bias: b0 -> A0 k=4j+2 (homogeneous coord); b1 -> C of L1 MFMA;
// b2 -> C of L2 MFMA; sum_t b3[t] + bias -> one scalar at the end.

constexpr int BATCH = 32768;
constexpr int FEAT  = 256;
constexpr int NTOW  = 128;
constexpr int U     = 4;    // 16-sample tiles per wave
constexpr int OUTN  = BATCH + NTOW;   // out + shape_loss

constexpr int REC = 544;  // dwords per tower record (2176 B, 16B-aligned)
// record layout (dword offsets): [0,512) = 64 lanes x 8 dwords
// {a0.lo,a0.hi,a1.lo,a1.hi,a2.lo,a2.hi,a3.lo,a3.hi};
// [512,528) = b1 f32[16]; [528,544) = b2 f32[16] (rows 8..15 = 0).
constexpr int OFF_B1 = 512, OFF_B2 = 528;

typedef _Float16 h4_t __attribute__((ext_vector_type(4)));
typedef __fp16   hp2_t __attribute__((ext_vector_type(2)));
typedef float    f4_t __attribute__((ext_vector_type(4)));

static __device__ __forceinline__ h4_t u2_to_h4(uint32_t lo, uint32_t hi) {
  union { uint2 u; h4_t h; } cv; cv.u.x = lo; cv.u.y = hi; return cv.h;
}
static __device__ __forceinline__ void h4_to_u2(h4_t v, uint32_t* d) {
  union { h4_t h; uint2 u; } cv; cv.h = v; d[0] = cv.u.x; d[1] = cv.u.y;
}
// pack 4 f32 -> 4 f16 (2x v_cvt_pkrtz) then packed relu (v_pk_max_f16 x2).
// relu(cvt(x)) == cvt(relu(x)): RTZ preserves sign; -0 is harmless in dots.
static __device__ __forceinline__ h4_t relu_pack4(const f4_t d) {
  const hp2_t lo = __builtin_amdgcn_cvt_pkrtz(d[0], d[1]);
  const hp2_t hi = __builtin_amdgcn_cvt_pkrtz(d[2], d[3]);
  h4_t r;
  r[0] = (_Float16)lo[0]; r[1] = (_Float16)lo[1];
  r[2] = (_Float16)hi[0]; r[3] = (_Float16)hi[1];
  const h4_t z = {(_Float16)0.f, (_Float16)0.f, (_Float16)0.f, (_Float16)0.f};
  return __builtin_elementwise_max(r, z);
}

__global__ void pack_frags(
    const float* __restrict__ W0, const float* __restrict__ B0,
    const float* __restrict__ W1, const float* __restrict__ B1,
    const float* __restrict__ W2, const float* __restrict__ B2,
    const float* __restrict__ W3, const float* __restrict__ B3,
    const float* __restrict__ bias, uint32_t* __restrict__ pack,
    float* __restrict__ out) {
  const int t   = blockIdx.x;
  const int l   = threadIdx.x;      // 64 threads = 64 lanes
  const int row = l & 15;           // A-frag row  = lane&15
  const int kg  = l >> 4;           // A-frag k    = (lane>>4)*4 + r
  uint32_t* rec = pack + t * REC;

  // Zero the output buffer (out[0:BATCH] accumulated by atomics;
  // shape_loss[BATCH:BATCH+NTOW] stays 0). Grid-stride over all blocks.
  for (int i = t * 64 + l; i < OUTN; i += NTOW * 64) out[i] = 0.f;

  h4_t a0, a1, a2, a3;
#pragma unroll
  for (int r = 0; r < 4; ++r) {
    const int k = kg * 4 + r;
    // A0: tower t occupies k-columns 4*(t&3) .. 4*(t&3)+2.
    float v0 = 0.f;
    if (kg == (t & 3)) {
      if (r < 2)       v0 = W0[(16*t + row) * FEAT + 2*t + r];
      else if (r == 2) v0 = B0[16*t + row];
    }
    a0[r] = (_Float16)v0;

    float v1 = 0.f;
    if (row < 12)    v1 = W1[(12*t + row) * (16*NTOW) + 16*t + k];
    a1[r] = (_Float16)v1;

    float v2 = 0.f;
    if (row < 8 && k < 12) v2 = W2[(8*t + row) * (12*NTOW) + 12*t + k];
    a2[r] = (_Float16)v2;

    float v3 = 0.f;
    if (row == 0 && k < 8) v3 = W3[t * (8*NTOW) + 8*t + k];
    a3[r] = (_Float16)v3;
  }
  uint32_t* lrec = rec + 8 * l;
  h4_to_u2(a0, lrec + 0);
  h4_to_u2(a1, lrec + 2);
  h4_to_u2(a2, lrec + 4);
  h4_to_u2(a3, lrec + 6);

  if (l < 16) {
    const float b1v = (l < 12) ? B1[12*t + l] : 0.f;
    rec[OFF_B1 + l] = __float_as_uint(b1v);
    const float b2v = (l < 8) ? B2[8*t + l] : 0.f;
    rec[OFF_B2 + l] = __float_as_uint(b2v);
  }
  if (t == 0 && l == 0) {
    float s = bias[0];
    for (int j = 0; j < NTOW; ++j) s += B3[j];
    pack[NTOW * REC] = __float_as_uint(s);
  }
}

// One wave: tower group g (16 towers), U tiles of 16 samples.
__global__ __launch_bounds__(256, 4) void bs_mfma(
    const float* __restrict__ x, const uint32_t* __restrict__ pack,
    float* __restrict__ out) {
  const int wid   = blockIdx.x * 4 + (threadIdx.x >> 6);
  const int lane  = threadIdx.x & 63;
  const int col   = lane & 15;       // sample within tile
  const int kg    = lane >> 4;
  const int g     = wid & 7;         // tower group: towers [16g, 16g+16)
  const int sbase = (wid >> 3) * (16 * U);

  const float cbias = __uint_as_float(pack[NTOW * REC]);
  const f4_t zc = {0.f, 0.f, 0.f, 0.f};

  // ---- preload all 16 B0 fragments (4 packs x U tiles) ----
  // Per-lane x base: sample row (sbase+col), feature 2*(16g + kg).
  const float* __restrict__ xb =
      x + (size_t)(sbase + col) * FEAT + 2 * (g * 16 + kg);
  h4_t b0[4 * U];
#pragma unroll
  for (int p = 0; p < 4; ++p)
#pragma unroll
    for (int u = 0; u < U; ++u) {
      const float2 xv = *(const float2*)(xb + 8 * p + (size_t)u * 16 * FEAT);
      const hp2_t xh = __builtin_amdgcn_cvt_pkrtz(xv.x, xv.y);
      h4_t b;
      b[0] = (_Float16)xh[0];
      b[1] = (_Float16)xh[1];
      b[2] = (_Float16)1.0f;
      b[3] = (_Float16)0.0f;
      b0[p * U + u] = b;
    }

  const uint32_t* __restrict__ fp  = pack + (size_t)(g * 16) * REC + 8 * lane;
  const uint32_t* __restrict__ bp1 = pack + (size_t)(g * 16) * REC + OFF_B1 + kg * 4;
  const uint32_t* __restrict__ bp2 = pack + (size_t)(g * 16) * REC + OFF_B2 + kg * 4;

  float accv[U];
#pragma unroll
  for (int u = 0; u < U; ++u) accv[u] = 0.f;

#pragma unroll
  for (int jp = 0; jp < 8; ++jp) {   // tower pairs (j0 = 2jp, j1 = 2jp+1)
    const int j0 = 2 * jp, j1 = 2 * jp + 1;
    const int p  = jp >> 1;          // b0 pack index

    const uint4  wA0 = *(const uint4*)(fp + j0 * REC);      // a0|a1 tower j0
    const uint4  wA1 = *(const uint4*)(fp + j1 * REC);      // a0|a1 tower j1
    const float4 cb10 = *(const float4*)(bp1 + j0 * REC);
    const float4 cb11 = *(const float4*)(bp1 + j1 * REC);
    const uint4  wB0 = *(const uint4*)(fp + j0 * REC + 4);  // a2|a3 tower j0
    const uint4  wB1 = *(const uint4*)(fp + j1 * REC + 4);  // a2|a3 tower j1
    const float4 cb20 = *(const float4*)(bp2 + j0 * REC);
    const float4 cb21 = *(const float4*)(bp2 + j1 * REC);

    const h4_t a0_0 = u2_to_h4(wA0.x, wA0.y), a1_0 = u2_to_h4(wA0.z, wA0.w);
    const h4_t a0_1 = u2_to_h4(wA1.x, wA1.y), a1_1 = u2_to_h4(wA1.z, wA1.w);
    const f4_t c1_0 = {cb10.x, cb10.y, cb10.z, cb10.w};
    const f4_t c1_1 = {cb11.x, cb11.y, cb11.z, cb11.w};

    // ---- Stage A: both towers' L0+L1, all U tiles (8 chains) ----
    h4_t h1_0[U], h1_1[U];
#pragma unroll
    for (int u = 0; u < U; ++u) {
      const f4_t d0 = __builtin_amdgcn_mfma_f32_16x16x16f16(a0_0, b0[p * U + u], zc, 0, 0, 0);
      const f4_t e0 = __builtin_amdgcn_mfma_f32_16x16x16f16(a0_1, b0[p * U + u], zc, 0, 0, 0);
      const h4_t h0 = relu_pack4(d0);
      const h4_t g0 = relu_pack4(e0);
      const f4_t d1 = __builtin_amdgcn_mfma_f32_16x16x16f16(a1_0, h0, c1_0, 0, 0, 0);
      const f4_t e1 = __builtin_amdgcn_mfma_f32_16x16x16f16(a1_1, g0, c1_1, 0, 0, 0);
      h1_0[u] = relu_pack4(d1);
      h1_1[u] = relu_pack4(e1);
    }

    const h4_t a2_0 = u2_to_h4(wB0.x, wB0.y), a3_0 = u2_to_h4(wB0.z, wB0.w);
    const h4_t a2_1 = u2_to_h4(wB1.x, wB1.y), a3_1 = u2_to_h4(wB1.z, wB1.w);
    const f4_t c2_0 = {cb20.x, cb20.y, cb20.z, cb20.w};
    const f4_t c2_1 = {cb21.x, cb21.y, cb21.z, cb21.w};

    // ---- Stage B: both towers' L2+L3 (8 chains); scalar accumulate ----
#pragma unroll
    for (int u = 0; u < U; ++u) {
      const f4_t d2 = __builtin_amdgcn_mfma_f32_16x16x16f16(a2_0, h1_0[u], c2_0, 0, 0, 0);
      const f4_t e2 = __builtin_amdgcn_mfma_f32_16x16x16f16(a2_1, h1_1[u], c2_1, 0, 0, 0);
      const h4_t h2 = relu_pack4(d2);
      const h4_t g2 = relu_pack4(e2);
      const f4_t d3 = __builtin_amdgcn_mfma_f32_16x16x16f16(a3_0, h2, zc, 0, 0, 0);
      const f4_t e3 = __builtin_amdgcn_mfma_f32_16x16x16f16(a3_1, g2, zc, 0, 0, 0);
      // Only row 0 (kg==0, reg 0) is nonzero; other lanes add 0.
      accv[u] += d3[0] + e3[0];
    }
  }

  if (kg == 0) {
    const float add = (g == 0) ? cbias : 0.f;
#pragma unroll
    for (int u = 0; u < U; ++u)
      atomicAdd(out + sbase + u * 16 + col, accv[u] + add);
  }
}

// ---- correctness-only fallback (ws too small; never expected) ----
__device__ __forceinline__ float gather_weight(
    int t, int i,
    const float* __restrict__ W0, const float* __restrict__ B0,
    const float* __restrict__ W1, const float* __restrict__ B1,
    const float* __restrict__ W2, const float* __restrict__ B2,
    const float* __restrict__ W3, const float* __restrict__ B3) {
  float v = 0.f;
  if (i < 32)       { int r = i >> 1, c = i & 1;               v = W0[(16*t + r)*FEAT + 2*t + c]; }
  else if (i < 48)  {                                           v = B0[16*t + (i - 32)]; }
  else if (i < 240) { int k = i - 48, r = k >> 4, c = k & 15;   v = W1[(12*t + r)*(16*NTOW) + 16*t + c]; }
  else if (i < 252) {                                           v = B1[12*t + (i - 240)]; }
  else if (i < 348) { int k = i - 252, r = k / 12, c = k - 12*r; v = W2[(8*t + r)*(12*NTOW) + 12*t + c]; }
  else if (i < 356) {                                           v = B2[8*t + (i - 348)]; }
  else if (i < 364) {                                           v = W3[t*(8*NTOW) + 8*t + (i - 356)]; }
  else if (i == 364){                                           v = B3[t]; }
  return v;
}

__global__ void bs_fwd_slow(
    const float* __restrict__ x,
    const float* __restrict__ W0, const float* __restrict__ B0,
    const float* __restrict__ W1, const float* __restrict__ B1,
    const float* __restrict__ W2, const float* __restrict__ B2,
    const float* __restrict__ W3, const float* __restrict__ B3,
    const float* __restrict__ bias,
    float* __restrict__ out) {
  const int s = blockIdx.x * blockDim.x + threadIdx.x;
  if (s >= BATCH) return;
  float acc = bias[0];
  for (int t = 0; t < NTOW; ++t) {
    float h0[16], h1[12], h2[8];
    const float x0 = x[(size_t)s*FEAT + 2*t], x1 = x[(size_t)s*FEAT + 2*t + 1];
    for (int r = 0; r < 16; ++r)
      h0[r] = fmaxf(0.f, gather_weight(t, 2*r, W0,B0,W1,B1,W2,B2,W3,B3) * x0
                        + gather_weight(t, 2*r+1, W0,B0,W1,B1,W2,B2,W3,B3) * x1
                        + gather_weight(t, 32+r, W0,B0,W1,B1,W2,B2,W3,B3));
    for (int r = 0; r < 12; ++r) {
      float sum = gather_weight(t, 240+r, W0,B0,W1,B1,W2,B2,W3,B3);
      for (int c = 0; c < 16; ++c)
        sum += gather_weight(t, 48+16*r+c, W0,B0,W1,B1,W2,B2,W3,B3) * h0[c];
      h1[r] = fmaxf(0.f, sum);
    }
    for (int r = 0; r < 8; ++r) {
      float sum = gather_weight(t, 348+r, W0,B0,W1,B1,W2,B2,W3,B3);
      for (int c = 0; c < 12; ++c)
        sum += gather_weight(t, 252+12*r+c, W0,B0,W1,B1,W2,B2,W3,B3) * h1[c];
      h2[r] = fmaxf(0.f, sum);
    }
    float sum = gather_weight(t, 364, W0,B0,W1,B1,W2,B2,W3,B3);
    for (int c = 0; c < 8; ++c)
      sum += gather_weight(t, 356+c, W0,B0,W1,B1,W2,B2,W3,B3) * h2[c];
    acc += sum;
  }
  out[s] = acc;
}

extern "C" void kernel_launch(void* const* d_in, const int* in_sizes, int n_in,
                              void* d_out, int out_size, void* d_ws, size_t ws_size,
                              hipStream_t stream) {
  const float* x    = (const float*)d_in[0];
  const float* W0   = (const float*)d_in[1];
  const float* B0   = (const float*)d_in[2];
  const float* W1   = (const float*)d_in[3];
  const float* B1   = (const float*)d_in[4];
  const float* W2   = (const float*)d_in[5];
  const float* B2   = (const float*)d_in[6];
  const float* W3   = (const float*)d_in[7];
  const float* B3   = (const float*)d_in[8];
  const float* bias = (const float*)d_in[9];
  float* out = (float*)d_out;

  const size_t packBytes = ((size_t)NTOW * REC + 1) * sizeof(uint32_t);

  if (ws_size >= packBytes) {
    uint32_t* pack = (uint32_t*)d_ws;
    // pack_frags also zeroes out[] (atomics accumulate; shape_loss stays 0).
    pack_frags<<<NTOW, 64, 0, stream>>>(W0, B0, W1, B1, W2, B2, W3, B3, bias, pack, out);
    const int waves = (BATCH / (16 * U)) * 8;     // 4096 waves
    bs_mfma<<<waves / 4, 256, 0, stream>>>(x, pack, out);
  } else {
    (void)hipMemsetAsync(d_out, 0, (size_t)out_size * sizeof(float), stream);
    bs_fwd_slow<<<BATCH / 256, 256, 0, stream>>>(x, W0, B0, W1, B1, W2, B2, W3, B3, bias, out);
  }
}